// Round 3
// baseline (1668.481 us; speedup 1.0000x reference)
//
#include <hip/hip_runtime.h>
#include <hip/hip_bf16.h>
#include <math.h>

#define B_ 32
#define N_ 256
#define E_ 1024
#define BN_ 8192

typedef __hip_bfloat16 bf16;
typedef __bf16 bf8v __attribute__((ext_vector_type(8)));
typedef float  f4v  __attribute__((ext_vector_type(4)));

__device__ __forceinline__ float b2f(bf16 v) {
    unsigned short u = *(unsigned short*)&v;
    return __uint_as_float(((unsigned)u) << 16);
}
__device__ __forceinline__ unsigned short f2bu(float f) {
    bf16 h = __float2bfloat16(f);
    return *(unsigned short*)&h;
}
__device__ __forceinline__ float4 load4bf(const bf16* p) {
    ushort4 u = *(const ushort4*)p;
    return make_float4(__uint_as_float((unsigned)u.x << 16),
                       __uint_as_float((unsigned)u.y << 16),
                       __uint_as_float((unsigned)u.z << 16),
                       __uint_as_float((unsigned)u.w << 16));
}
__device__ __forceinline__ void store4bf(bf16* p, float a, float b, float c, float d) {
    ushort4 u = make_ushort4(f2bu(a), f2bu(b), f2bu(c), f2bu(d));
    *(ushort4*)p = u;
}
__device__ __forceinline__ float safe_sigm(float x) {
    x = fminf(fmaxf(x, -40.0f), 40.0f);
    return 1.0f / (1.0f + expf(-x));
}
__device__ __forceinline__ float safe_tanh(float x) {
    x = fminf(fmaxf(x, -15.0f), 15.0f);
    float t = expf(2.0f * x);
    return (t - 1.0f) / (t + 1.0f);
}
// async global->LDS, 16B per lane; lds dest must be wave-uniform (HW adds lane*16)
__device__ __forceinline__ void glds16(const bf16* g, bf16* l) {
    __builtin_amdgcn_global_load_lds(
        (__attribute__((address_space(1))) const void*)g,
        (__attribute__((address_space(3))) void*)l, 16, 0, 0);
}

#define MFMA16(d, a, b) d = __builtin_amdgcn_mfma_f32_16x16x32_bf16(a, b, d, 0, 0, 0)

// ---------------------------------------------------------------------------
// fp32 -> bf16 conversion prepass (vectorized)
__global__ __launch_bounds__(256)
void w2bf_kernel(const float* __restrict__ src, bf16* __restrict__ dst, int n4)
{
    int i = blockIdx.x * 256 + threadIdx.x;
    if (i < n4) {
        float4 v = ((const float4*)src)[i];
        store4bf(dst + (size_t)i * 4, v.x, v.y, v.z, v.w);
    }
}

// ---------------------------------------------------------------------------
// Wg pack (encoder): row wr = e16*48 + gate*16 + eL, cols = [Wih row | Whh row]
__global__ __launch_bounds__(256)
void wgpack_kernel(const float* __restrict__ Wih, const float* __restrict__ Whh,
                   bf16* __restrict__ Wg)
{
    const int wr = blockIdx.x;                 // 0..3071
    const int e16 = wr / 48, rem = wr % 48;
    const int gate = rem >> 4, eL = rem & 15;
    const int e = e16 * 16 + eL;
    const float* s1 = Wih + (size_t)(gate * 1024 + e) * 2048;
    const float* s2 = Whh + (size_t)(gate * 1024 + e) * 1024;
    bf16* d = Wg + (size_t)wr * 3072;
    const int k0 = threadIdx.x * 4;
#pragma unroll
    for (int rep = 0; rep < 2; ++rep) {
        int k = k0 + rep * 1024;
        float4 v = *(const float4*)(s1 + k);
        store4bf(d + k, v.x, v.y, v.z, v.w);
    }
    {
        float4 v = *(const float4*)(s2 + k0);
        store4bf(d + 2048 + k0, v.x, v.y, v.z, v.w);
    }
}

// ---------------------------------------------------------------------------
// WgD pack (decoder): row wr = e16*48 + gate*16 + eL (e in [0,2048)), 1216 cols
__global__ __launch_bounds__(256)
void dgpack_kernel(const float* __restrict__ Wih, bf16* __restrict__ Wg)
{
    const int wr = blockIdx.x;                 // 0..6143
    const int e16 = wr / 48, rem = wr % 48;
    const int gate = rem >> 4, eL = rem & 15;
    const int e = e16 * 16 + eL;
    const float* s = Wih + (size_t)(gate * 2048 + e) * 1216;
    bf16* d = Wg + (size_t)wr * 1216;
    for (int k4 = threadIdx.x; k4 < 304; k4 += 256) {
        float4 v = *(const float4*)(s + k4 * 4);
        store4bf(d + k4 * 4, v.x, v.y, v.z, v.w);
    }
}

// ---------------------------------------------------------------------------
// h0 = annotation(8192,18) @ anno_W(18,1024) -> fp32
__global__ __launch_bounds__(256)
void anno_kernel(const float* __restrict__ anno, const float* __restrict__ W,
                 float* __restrict__ H)
{
    __shared__ float s[18];
    int row = blockIdx.x;
    if (threadIdx.x < 18) s[threadIdx.x] = anno[row * 18 + threadIdx.x];
    __syncthreads();
    for (int j = threadIdx.x; j < 1024; j += 256) {
        float acc = 0.0f;
#pragma unroll
        for (int k = 0; k < 18; ++k) acc = fmaf(s[k], W[k * 1024 + j], acc);
        H[(size_t)row * 1024 + j] = acc;
    }
}

// ---------------------------------------------------------------------------
// fp32 fallback: a = [A_out@H | A_in@H] per batch -> Abuf(8192,2048) bf16
__global__ __launch_bounds__(256)
void bmm_kernel(const float* __restrict__ Aout, const float* __restrict__ Ain,
                const float* __restrict__ H, bf16* __restrict__ Abuf)
{
    __shared__ float As[16][68];
    __shared__ float Bs[16][68];
    const int z = blockIdx.z;
    const int b = z >> 1, which = z & 1;
    const float* Amat = (which ? Ain : Aout) + (size_t)b * N_ * N_;
    const float* Bmat = H + (size_t)b * N_ * E_;
    const int t = threadIdx.x;
    const int tx = t & 15, ty = t >> 4;
    const int bm = blockIdx.x * 64;
    const int bn = blockIdx.y * 64;
    const int ar = t >> 2, ak = (t & 3) << 2;
    const int kr = t >> 4, kn = (t & 15) << 2;
    float acc[4][4] = {};
    for (int k0 = 0; k0 < N_; k0 += 16) {
        float4 av = *(const float4*)(Amat + (size_t)(bm + ar) * N_ + k0 + ak);
        As[ak + 0][ar] = av.x; As[ak + 1][ar] = av.y;
        As[ak + 2][ar] = av.z; As[ak + 3][ar] = av.w;
        float4 bv = *(const float4*)(Bmat + (size_t)(k0 + kr) * E_ + bn + kn);
        *(float4*)&Bs[kr][kn] = bv;
        __syncthreads();
#pragma unroll
        for (int kk = 0; kk < 16; ++kk) {
            float4 a4 = *(const float4*)&As[kk][ty << 2];
            float4 b4 = *(const float4*)&Bs[kk][tx << 2];
            float am[4] = {a4.x, a4.y, a4.z, a4.w};
            float bb[4] = {b4.x, b4.y, b4.z, b4.w};
#pragma unroll
            for (int i = 0; i < 4; ++i)
#pragma unroll
                for (int j = 0; j < 4; ++j)
                    acc[i][j] = fmaf(am[i], bb[j], acc[i][j]);
        }
        __syncthreads();
    }
#pragma unroll
    for (int i = 0; i < 4; ++i) {
        int row = b * N_ + bm + (ty << 2) + i;
        int col = which * 1024 + bn + (tx << 2);
        store4bf(&Abuf[(size_t)row * 2048 + col], acc[i][0], acc[i][1], acc[i][2], acc[i][3]);
    }
}

// ---------------------------------------------------------------------------
// H(b,256,1024) fp32 -> HbT(b,1024,256) bf16 (tiled transpose)
__global__ __launch_bounds__(256)
void htrans_kernel(const float* __restrict__ H, bf16* __restrict__ HbT)
{
    __shared__ float s[64][65];
    const int b = blockIdx.z;
    const int e0 = blockIdx.x * 64;
    const int n0 = blockIdx.y * 64;
    const float* Hb = H + (size_t)b * N_ * E_;
    bf16* Tb = HbT + (size_t)b * E_ * N_;
    const int t = threadIdx.x;
    const int tr = t >> 4, tc = (t & 15) << 2;
#pragma unroll
    for (int i = 0; i < 4; ++i) {
        float4 v = *(const float4*)(Hb + (size_t)(n0 + tr + i * 16) * E_ + e0 + tc);
        s[tr + i * 16][tc + 0] = v.x; s[tr + i * 16][tc + 1] = v.y;
        s[tr + i * 16][tc + 2] = v.z; s[tr + i * 16][tc + 3] = v.w;
    }
    __syncthreads();
#pragma unroll
    for (int i = 0; i < 4; ++i) {
        int e = tr + i * 16;
        store4bf(Tb + (size_t)(e0 + e) * N_ + n0 + tc,
                 s[tc + 0][e], s[tc + 1][e], s[tc + 2][e], s[tc + 3][e]);
    }
}

// ---------------------------------------------------------------------------
// MFMA bmm: out[m][n] = sum_k A(256x256)[m][k] * HbT(1024x256)[n][k] per (b,which)
__global__ __launch_bounds__(256)
void bmm_mfma_kernel(const bf16* __restrict__ Aoutb, const bf16* __restrict__ Ainb,
                     const bf16* __restrict__ HbT, bf16* __restrict__ Abuf)
{
    __shared__ bf16 As[64 * 32];
    __shared__ bf16 Bs[64 * 32];
    const int t = threadIdx.x;
    const int lane = t & 63, w = t >> 6;
    const int wm = (w >> 1) * 32, wn = (w & 1) * 32;
    const int z = blockIdx.z, b = z >> 1, which = z & 1;
    const int bm = blockIdx.x * 64, bn = blockIdx.y * 64;
    const int quad = lane >> 4, fr = lane & 15;
    const int srow = t >> 2, slot = t & 3;
    const int g = (slot + ((srow >> 1) & 3)) & 3;
    const int lds_off = srow * 32 + slot * 8;

    f4v acc[2][2];
#pragma unroll
    for (int i = 0; i < 2; ++i)
#pragma unroll
        for (int j = 0; j < 2; ++j) acc[i][j] = (f4v){0.f, 0.f, 0.f, 0.f};

    int aoff[2], boff[2];
#pragma unroll
    for (int i = 0; i < 2; ++i) {
        int arow = wm + 16 * i + fr;
        int s = (quad - ((arow >> 1) & 3)) & 3;
        aoff[i] = arow * 32 + s * 8;
    }
#pragma unroll
    for (int j = 0; j < 2; ++j) {
        int n = wn + 16 * j + fr;
        int s = (quad - ((n >> 1) & 3)) & 3;
        boff[j] = n * 32 + s * 8;
    }

    const bf16* Ap = (which ? Ainb : Aoutb) + (size_t)b * N_ * N_
                   + (size_t)(bm + srow) * N_ + g * 8;
    const bf16* Bp = HbT + (size_t)b * E_ * N_ + (size_t)(bn + srow) * N_ + g * 8;
    for (int k0 = 0; k0 < N_; k0 += 32) {
        float4 av = *(const float4*)(Ap + k0);
        float4 bv4 = *(const float4*)(Bp + k0);
        __syncthreads();
        *(float4*)(As + lds_off) = av;
        *(float4*)(Bs + lds_off) = bv4;
        __syncthreads();
        bf8v af0 = *(const bf8v*)(As + aoff[0]);
        bf8v af1 = *(const bf8v*)(As + aoff[1]);
#pragma unroll
        for (int j = 0; j < 2; ++j) {
            bf8v bv = *(const bf8v*)(Bs + boff[j]);
            MFMA16(acc[0][j], af0, bv);
            MFMA16(acc[1][j], af1, bv);
        }
    }
#pragma unroll
    for (int i = 0; i < 2; ++i)
#pragma unroll
        for (int j = 0; j < 2; ++j)
#pragma unroll
            for (int r = 0; r < 4; ++r) {
                int row = b * N_ + bm + wm + 16 * i + quad * 4 + r;
                int col = which * 1024 + bn + wn + 16 * j + fr;
                Abuf[(size_t)row * 2048 + col] = __float2bfloat16(acc[i][j][r]);
            }
}

// ---------------------------------------------------------------------------
// Fused encoder GRU step as ONE GEMM: X=[a(2048)|h(1024)] @ Wg(3072,3072)^T.
// Block 128(M) x 192(Wrows) = 64 e's x 3 gates. 4 waves, wave = 64 rows x 96 wcols.
// Phase 1 (K<2048): double-buffered glds16 prefetch, ONE barrier per K-step.
// Phase 2 (K>=2048): fp32 H inline-pack (2-barrier), n-gate to separate acc.
__global__ __launch_bounds__(256, 2)
void enc_gru_kernel(const bf16* __restrict__ Aab, const bf16* __restrict__ Wg,
                    const float* __restrict__ Hcur, float* __restrict__ Hnext)
{
    __shared__ __align__(16) bf16 As[2 * 128 * 32];   // 16 KB (2 bufs)
    __shared__ __align__(16) bf16 Bs[2 * 192 * 32];   // 24 KB (2 bufs)
    const int t = threadIdx.x;
    const int lane = t & 63, w = t >> 6;
    const int wm = (w >> 1) * 64;        // wave row base (0/64)
    const int wnH = (w & 1);             // wave e-half (0/1 -> +32 e)
    const int bm = blockIdx.x * 128;
    const int bY = blockIdx.y;           // e in [bY*64, bY*64+64)
    const int quad = lane >> 4, fr = lane & 15;

    f4v ar[2][4], az[2][4], ani[2][4], anh[2][4];
#pragma unroll
    for (int gq = 0; gq < 2; ++gq)
#pragma unroll
        for (int i = 0; i < 4; ++i) {
            ar[gq][i] = (f4v){0.f, 0.f, 0.f, 0.f};
            az[gq][i] = (f4v){0.f, 0.f, 0.f, 0.f};
            ani[gq][i] = (f4v){0.f, 0.f, 0.f, 0.f};
            anh[gq][i] = (f4v){0.f, 0.f, 0.f, 0.f};
        }

    // fragment read offsets (chunk-swizzled, zero-conflict)
    int aoff[4];
#pragma unroll
    for (int i = 0; i < 4; ++i) {
        int row = wm + 16 * i + fr;
        int s = (quad - ((row >> 1) & 3)) & 3;
        aoff[i] = row * 32 + s * 8;
    }
    int boff[2][3];
#pragma unroll
    for (int gq = 0; gq < 2; ++gq)
#pragma unroll
        for (int gt = 0; gt < 3; ++gt) {
            int nb = wnH * 96 + gq * 48 + gt * 16 + fr;
            int s = (quad - ((nb >> 1) & 3)) & 3;
            boff[gq][gt] = nb * 32 + s * 8;
        }

    // staging: lane -> (row-in-16 = lane>>2, slot = lane&3); source chunk g
    const int sr = lane >> 2, ss = lane & 3;
    const int lrA0 = w * 16 + sr;
    const int lrA1 = 64 + w * 16 + sr;
    const int gA0 = (ss + ((lrA0 >> 1) & 3)) & 3;
    const int gA1 = (ss + ((lrA1 >> 1) & 3)) & 3;
    const bf16* apA0 = Aab + (size_t)(bm + lrA0) * 2048 + gA0 * 8;
    const bf16* apA1 = Aab + (size_t)(bm + lrA1) * 2048 + gA1 * 8;
    const int lrB0 = w * 16 + sr, lrB1 = 64 + w * 16 + sr, lrB2 = 128 + w * 16 + sr;
    const int gB0 = (ss + ((lrB0 >> 1) & 3)) & 3;
    const int gB1 = (ss + ((lrB1 >> 1) & 3)) & 3;
    const int gB2 = (ss + ((lrB2 >> 1) & 3)) & 3;
    const bf16* bp0 = Wg + (size_t)(bY * 192 + lrB0) * 3072 + gB0 * 8;
    const bf16* bp1 = Wg + (size_t)(bY * 192 + lrB1) * 3072 + gB1 * 8;
    const bf16* bp2 = Wg + (size_t)(bY * 192 + lrB2) * 3072 + gB2 * 8;
    const int oA0 = (w * 16) * 32, oA1 = (64 + w * 16) * 32;
    const int oB0 = (w * 16) * 32, oB1 = (64 + w * 16) * 32, oB2 = (128 + w * 16) * 32;

#define ENC_STEP(Ab, Bb, AN) do {                                              \
    bf8v af0 = *(const bf8v*)((Ab) + aoff[0]);                                 \
    bf8v af1 = *(const bf8v*)((Ab) + aoff[1]);                                 \
    bf8v af2 = *(const bf8v*)((Ab) + aoff[2]);                                 \
    bf8v af3 = *(const bf8v*)((Ab) + aoff[3]);                                 \
    _Pragma("unroll")                                                          \
    for (int gq = 0; gq < 2; ++gq) {                                           \
        bf8v br_ = *(const bf8v*)((Bb) + boff[gq][0]);                         \
        bf8v bz_ = *(const bf8v*)((Bb) + boff[gq][1]);                         \
        bf8v bn_ = *(const bf8v*)((Bb) + boff[gq][2]);                         \
        MFMA16(ar[gq][0], af0, br_); MFMA16(ar[gq][1], af1, br_);              \
        MFMA16(ar[gq][2], af2, br_); MFMA16(ar[gq][3], af3, br_);              \
        MFMA16(az[gq][0], af0, bz_); MFMA16(az[gq][1], af1, bz_);              \
        MFMA16(az[gq][2], af2, bz_); MFMA16(az[gq][3], af3, bz_);              \
        MFMA16(AN[gq][0], af0, bn_); MFMA16(AN[gq][1], af1, bn_);              \
        MFMA16(AN[gq][2], af2, bn_); MFMA16(AN[gq][3], af3, bn_);              \
    }                                                                          \
} while (0)

    // ---- phase 1: k in [0, 2048), double-buffered prefetch, 1 barrier/step ----
    glds16(apA0, As + oA0);
    glds16(apA1, As + oA1);
    glds16(bp0, Bs + oB0);
    glds16(bp1, Bs + oB1);
    glds16(bp2, Bs + oB2);
    __syncthreads();                       // drains vmcnt before reads
    int cur = 0;
    for (int k0 = 0; k0 < 2048; k0 += 32) {
        const int nb = cur ^ 1;
        if (k0 + 32 < 2048) {
            glds16(apA0 + k0 + 32, As + nb * 4096 + oA0);
            glds16(apA1 + k0 + 32, As + nb * 4096 + oA1);
            glds16(bp0 + k0 + 32, Bs + nb * 6144 + oB0);
            glds16(bp1 + k0 + 32, Bs + nb * 6144 + oB1);
            glds16(bp2 + k0 + 32, Bs + nb * 6144 + oB2);
        }
        const bf16* Ab = As + cur * 4096;
        const bf16* Bb = Bs + cur * 6144;
        ENC_STEP(Ab, Bb, ani);
        __syncthreads();                   // drains this iter's glds too
        cur = nb;
    }

    // ---- phase 2: k in [2048, 3072) — h-part (fp32 inline->bf16), n -> anh ----
    {
        const int tr = t >> 1;                 // A-tile row 0..127
        const int c0 = (t & 1) * 2;            // chunks c0, c0+1
        const int rr_ = (tr >> 1) & 3;
        const int s0 = (c0 - rr_) & 3;
        const int s1 = (c0 + 1 - rr_) & 3;
        const float* hp = Hcur + (size_t)(bm + tr) * 1024 + c0 * 8;
        for (int k0 = 2048; k0 < 3072; k0 += 32) {
            const int k2 = k0 - 2048;
            float4 f0 = *(const float4*)(hp + k2);
            float4 f1 = *(const float4*)(hp + k2 + 4);
            float4 f2 = *(const float4*)(hp + k2 + 8);
            float4 f3 = *(const float4*)(hp + k2 + 12);
            uint4 u0, u1;
            u0.x = (unsigned)f2bu(f0.x) | ((unsigned)f2bu(f0.y) << 16);
            u0.y = (unsigned)f2bu(f0.z) | ((unsigned)f2bu(f0.w) << 16);
            u0.z = (unsigned)f2bu(f1.x) | ((unsigned)f2bu(f1.y) << 16);
            u0.w = (unsigned)f2bu(f1.z) | ((unsigned)f2bu(f1.w) << 16);
            u1.x = (unsigned)f2bu(f2.x) | ((unsigned)f2bu(f2.y) << 16);
            u1.y = (unsigned)f2bu(f2.z) | ((unsigned)f2bu(f2.w) << 16);
            u1.z = (unsigned)f2bu(f3.x) | ((unsigned)f2bu(f3.y) << 16);
            u1.w = (unsigned)f2bu(f3.z) | ((unsigned)f2bu(f3.w) << 16);
            __syncthreads();
            *(uint4*)(As + tr * 32 + s0 * 8) = u0;
            *(uint4*)(As + tr * 32 + s1 * 8) = u1;
            glds16(bp0 + k0, Bs + oB0);
            glds16(bp1 + k0, Bs + oB1);
            glds16(bp2 + k0, Bs + oB2);
            __syncthreads();
            ENC_STEP(As, Bs, anh);
        }
    }

    // ---- GRU gate epilogue: all 4 gate values per (row,e) in same lane/reg ----
#pragma unroll
    for (int gq = 0; gq < 2; ++gq) {
        const int e = bY * 64 + wnH * 32 + gq * 16 + fr;
#pragma unroll
        for (int i = 0; i < 4; ++i) {
#pragma unroll
            for (int r = 0; r < 4; ++r) {
                const int row = bm + wm + 16 * i + quad * 4 + r;
                float hv = Hcur[(size_t)row * 1024 + e];
                float rg = safe_sigm(ar[gq][i][r]);
                float zg = safe_sigm(az[gq][i][r]);
                float ng = safe_tanh(ani[gq][i][r] + rg * anh[gq][i][r]);
                Hnext[(size_t)row * 1024 + e] = (1.0f - zg) * ng + zg * hv;
            }
        }
    }
#undef ENC_STEP
}

// ---------------------------------------------------------------------------
// Fused decoder GRU as ONE GEMM: Cc(8192x1216) @ WgD(6144,1216)^T, h0=0.
// Same 128x192 geometry as enc; pure-bf16 A -> fully double-buffered glds16,
// one barrier per K-step (38 steps). hidden = (1-z)*n (fp32).
__global__ __launch_bounds__(256, 2)
void dec_gru_kernel(const bf16* __restrict__ Cc, const bf16* __restrict__ Wg,
                    const float* __restrict__ bih, const float* __restrict__ bhh,
                    float* __restrict__ hidden)
{
    __shared__ __align__(16) bf16 As[2 * 128 * 32];
    __shared__ __align__(16) bf16 Bs[2 * 192 * 32];
    const int t = threadIdx.x;
    const int lane = t & 63, w = t >> 6;
    const int wm = (w >> 1) * 64;
    const int wnH = (w & 1);
    const int bm = blockIdx.x * 128;
    const int bY = blockIdx.y;           // e in [bY*64, bY*64+64), e < 2048
    const int quad = lane >> 4, fr = lane & 15;

    f4v ag[3][2][4];                     // gate, gq, row-frag
#pragma unroll
    for (int c = 0; c < 3; ++c)
#pragma unroll
        for (int gq = 0; gq < 2; ++gq)
#pragma unroll
            for (int i = 0; i < 4; ++i) ag[c][gq][i] = (f4v){0.f, 0.f, 0.f, 0.f};

    int aoff[4];
#pragma unroll
    for (int i = 0; i < 4; ++i) {
        int row = wm + 16 * i + fr;
        int s = (quad - ((row >> 1) & 3)) & 3;
        aoff[i] = row * 32 + s * 8;
    }
    int boff[2][3];
#pragma unroll
    for (int gq = 0; gq < 2; ++gq)
#pragma unroll
        for (int gt = 0; gt < 3; ++gt) {
            int nb = wnH * 96 + gq * 48 + gt * 16 + fr;
            int s = (quad - ((nb >> 1) & 3)) & 3;
            boff[gq][gt] = nb * 32 + s * 8;
        }

    const int sr = lane >> 2, ss = lane & 3;
    const int lrA0 = w * 16 + sr;
    const int lrA1 = 64 + w * 16 + sr;
    const int gA0 = (ss + ((lrA0 >> 1) & 3)) & 3;
    const int gA1 = (ss + ((lrA1 >> 1) & 3)) & 3;
    const bf16* apA0 = Cc + (size_t)(bm + lrA0) * 1216 + gA0 * 8;
    const bf16* apA1 = Cc + (size_t)(bm + lrA1) * 1216 + gA1 * 8;
    const int lrB0 = w * 16 + sr, lrB1 = 64 + w * 16 + sr, lrB2 = 128 + w * 16 + sr;
    const int gB0 = (ss + ((lrB0 >> 1) & 3)) & 3;
    const int gB1 = (ss + ((lrB1 >> 1) & 3)) & 3;
    const int gB2 = (ss + ((lrB2 >> 1) & 3)) & 3;
    const bf16* bp0 = Wg + (size_t)(bY * 192 + lrB0) * 1216 + gB0 * 8;
    const bf16* bp1 = Wg + (size_t)(bY * 192 + lrB1) * 1216 + gB1 * 8;
    const bf16* bp2 = Wg + (size_t)(bY * 192 + lrB2) * 1216 + gB2 * 8;
    const int oA0 = (w * 16) * 32, oA1 = (64 + w * 16) * 32;
    const int oB0 = (w * 16) * 32, oB1 = (64 + w * 16) * 32, oB2 = (128 + w * 16) * 32;

    glds16(apA0, As + oA0);
    glds16(apA1, As + oA1);
    glds16(bp0, Bs + oB0);
    glds16(bp1, Bs + oB1);
    glds16(bp2, Bs + oB2);
    __syncthreads();
    int cur = 0;
    for (int k0 = 0; k0 < 1216; k0 += 32) {
        const int nb = cur ^ 1;
        if (k0 + 32 < 1216) {
            glds16(apA0 + k0 + 32, As + nb * 4096 + oA0);
            glds16(apA1 + k0 + 32, As + nb * 4096 + oA1);
            glds16(bp0 + k0 + 32, Bs + nb * 6144 + oB0);
            glds16(bp1 + k0 + 32, Bs + nb * 6144 + oB1);
            glds16(bp2 + k0 + 32, Bs + nb * 6144 + oB2);
        }
        const bf16* Ab = As + cur * 4096;
        const bf16* Bb = Bs + cur * 6144;
        bf8v af0 = *(const bf8v*)(Ab + aoff[0]);
        bf8v af1 = *(const bf8v*)(Ab + aoff[1]);
        bf8v af2 = *(const bf8v*)(Ab + aoff[2]);
        bf8v af3 = *(const bf8v*)(Ab + aoff[3]);
#pragma unroll
        for (int gq = 0; gq < 2; ++gq) {
            bf8v br_ = *(const bf8v*)(Bb + boff[gq][0]);
            bf8v bz_ = *(const bf8v*)(Bb + boff[gq][1]);
            bf8v bn_ = *(const bf8v*)(Bb + boff[gq][2]);
            MFMA16(ag[0][gq][0], af0, br_); MFMA16(ag[0][gq][1], af1, br_);
            MFMA16(ag[0][gq][2], af2, br_); MFMA16(ag[0][gq][3], af3, br_);
            MFMA16(ag[1][gq][0], af0, bz_); MFMA16(ag[1][gq][1], af1, bz_);
            MFMA16(ag[1][gq][2], af2, bz_); MFMA16(ag[1][gq][3], af3, bz_);
            MFMA16(ag[2][gq][0], af0, bn_); MFMA16(ag[2][gq][1], af1, bn_);
            MFMA16(ag[2][gq][2], af2, bn_); MFMA16(ag[2][gq][3], af3, bn_);
        }
        __syncthreads();
        cur = nb;
    }

#pragma unroll
    for (int gq = 0; gq < 2; ++gq) {
        const int e = bY * 64 + wnH * 32 + gq * 16 + fr;
        const float br = bih[e] + bhh[e];
        const float bz = bih[2048 + e] + bhh[2048 + e];
        const float bni = bih[4096 + e];
        const float bnh = bhh[4096 + e];
#pragma unroll
        for (int i = 0; i < 4; ++i) {
#pragma unroll
            for (int r = 0; r < 4; ++r) {
                const int row = bm + wm + 16 * i + quad * 4 + r;
                float rr = safe_sigm(ag[0][gq][i][r] + br);
                float zz = safe_sigm(ag[1][gq][i][r] + bz);
                float nn = safe_tanh(ag[2][gq][i][r] + bni + rr * bnh);
                hidden[(size_t)row * 2048 + e] = (1.0f - zz) * nn;
            }
        }
    }
}

// ---------------------------------------------------------------------------
__global__ __launch_bounds__(128)
void vnva_kernel(const float* __restrict__ vnf_now, const float* __restrict__ vnf_all,
                 const float* __restrict__ Wn, const float* __restrict__ Wa,
                 float* __restrict__ vn, float* __restrict__ va)
{
    int b = blockIdx.x, t = threadIdx.x;
    if (t < 64) {
        float s = 0.f;
#pragma unroll
        for (int k = 0; k < 16; ++k) s = fmaf(vnf_now[b * 16 + k], Wn[k * 64 + t], s);
        vn[b * 64 + t] = s;
    } else {
        int d = t - 64;
        float s = 0.f;
#pragma unroll
        for (int k = 0; k < 16; ++k) s = fmaf(vnf_all[b * 16 + k], Wa[k * 64 + d], s);
        va[b * 64 + d] = s;
    }
}

// concat(row,1216) = [ enc_out(1024) | npos(64) | va(64) | vn(64) ] -> bf16
__global__ __launch_bounds__(256)
void concat_kernel(const float* __restrict__ H, const float* __restrict__ pos_enc,
                   const int* __restrict__ from_node, const float* __restrict__ va,
                   const float* __restrict__ vn, bf16* __restrict__ Cc)
{
    int row = blockIdx.x;
    int b = row >> 8;
    int fn = from_node[b];
    bf16* dst = Cc + (size_t)row * 1216;
    for (int c = threadIdx.x; c < 1216; c += 256) {
        float v;
        if (c < 1024)      v = H[(size_t)row * 1024 + c];
        else if (c < 1088) v = pos_enc[fn * 64 + (c - 1024)];
        else if (c < 1152) v = va[b * 64 + (c - 1088)];
        else               v = vn[b * 64 + (c - 1152)];
        dst[c] = __float2bfloat16(v);
    }
}

// ---------------------------------------------------------------------------
// MFMA out1: mid = relu(hidden(8192x2048 fp32, inline->bf16) @ W1b^T + b1) -> bf16
__global__ __launch_bounds__(256)
void out1_mfma_kernel(const float* __restrict__ H, const bf16* __restrict__ W1b,
                      const float* __restrict__ bias, bf16* __restrict__ mid)
{
    __shared__ bf16 As[64 * 32];
    __shared__ bf16 Ws[256 * 32];
    const int t = threadIdx.x;
    const int lane = t & 63, w = t >> 6;
    const int bm = blockIdx.x * 64, bn = blockIdx.y * 256;
    const int quad = lane >> 4, fr = lane & 15;
    const int srow = t >> 2, slot = t & 3;
    const int g = (slot + ((srow >> 1) & 3)) & 3;
    const int lds_off = srow * 32 + slot * 8;

    f4v acc[4][4];
#pragma unroll
    for (int i = 0; i < 4; ++i)
#pragma unroll
        for (int j = 0; j < 4; ++j) acc[i][j] = (f4v){0.f, 0.f, 0.f, 0.f};

    int aoff[4], boff[4];
#pragma unroll
    for (int i = 0; i < 4; ++i) {
        int arow = 16 * i + fr;
        int s = (quad - ((arow >> 1) & 3)) & 3;
        aoff[i] = arow * 32 + s * 8;
    }
#pragma unroll
    for (int j = 0; j < 4; ++j) {
        int n = w * 64 + 16 * j + fr;
        int s = (quad - ((n >> 1) & 3)) & 3;
        boff[j] = n * 32 + s * 8;
    }

    const float* Hp = H + (size_t)(bm + srow) * 2048 + g * 8;
    const bf16* Wp0 = W1b + (size_t)(bn + srow) * 2048 + g * 8;
    const bf16* Wp1 = W1b + (size_t)(bn + srow + 64) * 2048 + g * 8;
    const bf16* Wp2 = W1b + (size_t)(bn + srow + 128) * 2048 + g * 8;
    const bf16* Wp3 = W1b + (size_t)(bn + srow + 192) * 2048 + g * 8;

    for (int k0 = 0; k0 < 2048; k0 += 32) {
        float4 h0 = *(const float4*)(Hp + k0);
        float4 h1 = *(const float4*)(Hp + k0 + 4);
        float4 w0 = *(const float4*)(Wp0 + k0);
        float4 w1 = *(const float4*)(Wp1 + k0);
        float4 w2 = *(const float4*)(Wp2 + k0);
        float4 w3 = *(const float4*)(Wp3 + k0);
        uint4 pk;
        pk.x = (unsigned)f2bu(h0.x) | ((unsigned)f2bu(h0.y) << 16);
        pk.y = (unsigned)f2bu(h0.z) | ((unsigned)f2bu(h0.w) << 16);
        pk.z = (unsigned)f2bu(h1.x) | ((unsigned)f2bu(h1.y) << 16);
        pk.w = (unsigned)f2bu(h1.z) | ((unsigned)f2bu(h1.w) << 16);
        __syncthreads();
        *(uint4*)(As + lds_off) = pk;
        *(float4*)(Ws + lds_off) = w0;
        *(float4*)(Ws + 2048 + lds_off) = w1;
        *(float4*)(Ws + 4096 + lds_off) = w2;
        *(float4*)(Ws + 6144 + lds_off) = w3;
        __syncthreads();
        bf8v af0 = *(const bf8v*)(As + aoff[0]);
        bf8v af1 = *(const bf8v*)(As + aoff[1]);
        bf8v af2 = *(const bf8v*)(As + aoff[2]);
        bf8v af3 = *(const bf8v*)(As + aoff[3]);
#pragma unroll
        for (int j = 0; j < 4; ++j) {
            bf8v bv = *(const bf8v*)(Ws + boff[j]);
            MFMA16(acc[0][j], af0, bv);
            MFMA16(acc[1][j], af1, bv);
            MFMA16(acc[2][j], af2, bv);
            MFMA16(acc[3][j], af3, bv);
        }
    }
#pragma unroll
    for (int j = 0; j < 4; ++j) {
        const int col = bn + w * 64 + 16 * j + fr;
        const float bb = bias[col];
#pragma unroll
        for (int i = 0; i < 4; ++i) {
#pragma unroll
            for (int r = 0; r < 4; ++r) {
                const int row = bm + 16 * i + quad * 4 + r;
                mid[(size_t)row * 1024 + col] = __float2bfloat16(fmaxf(acc[i][j][r] + bb, 0.0f));
            }
        }
    }
}

// ---------------------------------------------------------------------------
__global__ __launch_bounds__(64)
void out2_kernel(const bf16* __restrict__ mid, const float* __restrict__ W2,
                 const float* __restrict__ b2, float* __restrict__ outb)
{
    int row = blockIdx.x, t = threadIdx.x;
    float s0 = 0.f, s1 = 0.f, s2 = 0.f;
    for (int k = t; k < 1024; k += 64) {
        float m = b2f(mid[(size_t)row * 1024 + k]);
        s0 = fmaf(m, W2[k], s0);
        s1 = fmaf(m, W2[1024 + k], s1);
        s2 = fmaf(m, W2[2048 + k], s2);
    }
#pragma unroll
    for (int off = 32; off > 0; off >>= 1) {
        s0 += __shfl_down(s0, off, 64);
        s1 += __shfl_down(s1, off, 64);
        s2 += __shfl_down(s2, off, 64);
    }
    if (t == 0) {
        outb[row * 3 + 0] = s0 + b2[0];
        outb[row * 3 + 1] = s1 + b2[1];
        outb[row * 3 + 2] = s2 + b2[2];
    }
}

__global__ __launch_bounds__(64)
void max_kernel(const float* __restrict__ outb, float* __restrict__ maxb)
{
    int b = blockIdx.x, t = threadIdx.x;
    float m = -3.0e38f;
    for (int i = t; i < 768; i += 64) m = fmaxf(m, outb[b * 768 + i]);
#pragma unroll
    for (int off = 32; off > 0; off >>= 1) m = fmaxf(m, __shfl_down(m, off, 64));
    if (t == 0) maxb[b] = m;
}

__global__ __launch_bounds__(256)
void mask_kernel(const float* __restrict__ outb, const float* __restrict__ maxb,
                 const int* __restrict__ mask, float* __restrict__ out)
{
    int idx = blockIdx.x * 256 + threadIdx.x;
    if (idx >= BN_ * 3) return;
    int row = idx / 3, c = idx - row * 3;
    int b = row >> 8;
    float v = outb[idx] - (maxb[b] + 1.0f);
    float mf = (mask[row] == 1) ? 1.0f : 1e10f;
    v = mf * v + 1.0f;
    if (c == 0) out[row] = v;
    else        out[8192 + row * 2 + (c - 1)] = v;
}

// ---------------------------------------------------------------------------
extern "C" void kernel_launch(void* const* d_in, const int* in_sizes, int n_in,
                              void* d_out, int out_size, void* d_ws, size_t ws_size,
                              hipStream_t stream)
{
    const float* annotation = (const float*)d_in[0];
    const float* A_out      = (const float*)d_in[1];
    const float* A_in       = (const float*)d_in[2];
    const int*   from_node  = (const int*)d_in[3];
    const float* vnf_now    = (const float*)d_in[4];
    const float* vnf_all    = (const float*)d_in[5];
    const int*   mask       = (const int*)d_in[6];
    const float* anno_W     = (const float*)d_in[7];
    const float* gru_Wih    = (const float*)d_in[8];
    const float* gru_Whh    = (const float*)d_in[9];
    const float* vnf_now_W  = (const float*)d_in[10];
    const float* vnf_all_W  = (const float*)d_in[11];
    const float* dgru_Wih   = (const float*)d_in[12];
    // d_in[13] dgru_Whh dead: h0 == 0
    const float* dgru_bih   = (const float*)d_in[14];
    const float* dgru_bhh   = (const float*)d_in[15];
    const float* out_W1     = (const float*)d_in[16];
    const float* out_b1     = (const float*)d_in[17];
    const float* out_W2     = (const float*)d_in[18];
    const float* out_b2     = (const float*)d_in[19];
    const float* pos_enc    = (const float*)d_in[20];
    float* out = (float*)d_out;

    // ws layout (identical footprint to round 2):
    //   base (52.5 MB): Abuf bf16 (33.55) + Wenc bf16 (18.87, time-shared:
    //     Wg during enc -> WgD for dec -> W1b for out1) + fbuf small
    //   full (+25.2 MB): Aoutb/Ainb bf16 (8.39) + HbT bf16 (16.78)
    bf16*  Abuf = (bf16*)d_ws;                        // 8192*2048
    bf16*  Wenc = Abuf + (size_t)8192 * 2048;         // 9,437,184 bf16
    bf16*  Wg   = Wenc;                               // 3072*3072 == 9,437,184
    bf16*  WgD  = Wenc;                               // 6144*1216 fits
    bf16*  W1b  = Wenc;                               // 1024*2048 fits
    float* fbuf = (float*)(Wenc + (size_t)9437184);
    float* vnb  = fbuf;            // 32*64
    float* vab  = vnb + 2048;      // 32*64
    float* outb = vab + 2048;      // 8192*3
    float* maxb = outb + 24576;    // 32
    bf16*  Aoutb = (bf16*)(maxb + 32);                // 32*256*256
    bf16*  Ainb  = Aoutb + (size_t)32 * 256 * 256;    // 32*256*256
    bf16*  HbT   = Ainb + (size_t)32 * 256 * 256;     // 32*1024*256

    const size_t NEED_FULL = (size_t)(16777216 + 9437184) * 2 + 28704 * 4
                           + (size_t)(4194304 + 8388608) * 2;   // 77,709,440 B
    const bool full = ws_size >= NEED_FULL;

    // fp32 H ping-pong inside d_out's hidden slot
    float* hidden = out + 24576;
    float* H0 = hidden;
    float* H1 = H0 + (size_t)8192 * 1024;
    bf16* Cc  = Abuf;              // concat 8192x1216 bf16 (after a dead)
    bf16* mid = Abuf;              // 8192x1024 bf16 (after concat dead)

    // weight prepass (same work every launch — graph-capture safe)
    wgpack_kernel<<<3072, 256, 0, stream>>>(gru_Wih, gru_Whh, Wg);
    if (full) {
        w2bf_kernel<<<2048, 256, 0, stream>>>(A_out, Aoutb, 32 * 256 * 256 / 4);
        w2bf_kernel<<<2048, 256, 0, stream>>>(A_in,  Ainb,  32 * 256 * 256 / 4);
    }

    anno_kernel<<<8192, 256, 0, stream>>>(annotation, anno_W, H0);

    const float* hc = H0;
    float* hn = H1;
    for (int s = 0; s < 5; ++s) {
        if (full) {
            htrans_kernel<<<dim3(16, 4, 32), 256, 0, stream>>>(hc, HbT);
            bmm_mfma_kernel<<<dim3(4, 16, 64), 256, 0, stream>>>(Aoutb, Ainb, HbT, Abuf);
        } else {
            bmm_kernel<<<dim3(4, 16, 64), 256, 0, stream>>>(A_out, A_in, hc, Abuf);
        }
        enc_gru_kernel<<<dim3(64, 16), 256, 0, stream>>>(Abuf, Wg, hc, hn);
        float* tmp = (float*)hc; hc = hn; hn = tmp;
    }
    // hc == H1 after 5 steps

    vnva_kernel<<<32, 128, 0, stream>>>(vnf_now, vnf_all, vnf_now_W, vnf_all_W, vnb, vab);
    concat_kernel<<<8192, 256, 0, stream>>>(hc, pos_enc, from_node, vab, vnb, Cc);

    // enc weights dead -> pack decoder weight into the same region
    dgpack_kernel<<<6144, 256, 0, stream>>>(dgru_Wih, WgD);
    dec_gru_kernel<<<dim3(64, 32), 256, 0, stream>>>(Cc, WgD, dgru_bih, dgru_bhh, hidden);

    // decoder weight dead -> convert out_W1 into the same region
    w2bf_kernel<<<2048, 256, 0, stream>>>(out_W1, W1b, 1024 * 2048 / 4);
    out1_mfma_kernel<<<dim3(128, 4), 256, 0, stream>>>(hidden, W1b, out_b1, mid);

    out2_kernel<<<8192, 64, 0, stream>>>(mid, out_W2, out_b2, outb);
    max_kernel<<<32, 64, 0, stream>>>(outb, maxb);
    mask_kernel<<<96, 256, 0, stream>>>(outb, maxb, mask, out);
}

// Round 4
// 1511.694 us; speedup vs baseline: 1.1037x; 1.1037x over previous
//
#include <hip/hip_runtime.h>
#include <hip/hip_bf16.h>
#include <math.h>

#define B_ 32
#define N_ 256
#define E_ 1024
#define BN_ 8192

typedef __hip_bfloat16 bf16;
typedef __bf16 bf8v __attribute__((ext_vector_type(8)));
typedef float  f4v  __attribute__((ext_vector_type(4)));

__device__ __forceinline__ float b2f(bf16 v) {
    unsigned short u = *(unsigned short*)&v;
    return __uint_as_float(((unsigned)u) << 16);
}
__device__ __forceinline__ unsigned short f2bu(float f) {
    bf16 h = __float2bfloat16(f);
    return *(unsigned short*)&h;
}
__device__ __forceinline__ float4 load4bf(const bf16* p) {
    ushort4 u = *(const ushort4*)p;
    return make_float4(__uint_as_float((unsigned)u.x << 16),
                       __uint_as_float((unsigned)u.y << 16),
                       __uint_as_float((unsigned)u.z << 16),
                       __uint_as_float((unsigned)u.w << 16));
}
__device__ __forceinline__ void store4bf(bf16* p, float a, float b, float c, float d) {
    ushort4 u = make_ushort4(f2bu(a), f2bu(b), f2bu(c), f2bu(d));
    *(ushort4*)p = u;
}
__device__ __forceinline__ float safe_sigm(float x) {
    x = fminf(fmaxf(x, -40.0f), 40.0f);
    return 1.0f / (1.0f + expf(-x));
}
__device__ __forceinline__ float safe_tanh(float x) {
    x = fminf(fmaxf(x, -15.0f), 15.0f);
    float t = expf(2.0f * x);
    return (t - 1.0f) / (t + 1.0f);
}
// async global->LDS, 16B per lane; lds dest must be wave-uniform (HW adds lane*16)
__device__ __forceinline__ void glds16(const bf16* g, bf16* l) {
    __builtin_amdgcn_global_load_lds(
        (__attribute__((address_space(1))) const void*)g,
        (__attribute__((address_space(3))) void*)l, 16, 0, 0);
}

#define MFMA16(d, a, b) d = __builtin_amdgcn_mfma_f32_16x16x32_bf16(a, b, d, 0, 0, 0)

// ---------------------------------------------------------------------------
// fp32 -> bf16 conversion prepass (vectorized)
__global__ __launch_bounds__(256)
void w2bf_kernel(const float* __restrict__ src, bf16* __restrict__ dst, int n4)
{
    int i = blockIdx.x * 256 + threadIdx.x;
    if (i < n4) {
        float4 v = ((const float4*)src)[i];
        store4bf(dst + (size_t)i * 4, v.x, v.y, v.z, v.w);
    }
}

// ---------------------------------------------------------------------------
// Wg pack (encoder): row wr = e16*48 + gate*16 + eL, cols = [Wih row | Whh row]
__global__ __launch_bounds__(256)
void wgpack_kernel(const float* __restrict__ Wih, const float* __restrict__ Whh,
                   bf16* __restrict__ Wg)
{
    const int wr = blockIdx.x;                 // 0..3071
    const int e16 = wr / 48, rem = wr % 48;
    const int gate = rem >> 4, eL = rem & 15;
    const int e = e16 * 16 + eL;
    const float* s1 = Wih + (size_t)(gate * 1024 + e) * 2048;
    const float* s2 = Whh + (size_t)(gate * 1024 + e) * 1024;
    bf16* d = Wg + (size_t)wr * 3072;
    const int k0 = threadIdx.x * 4;
#pragma unroll
    for (int rep = 0; rep < 2; ++rep) {
        int k = k0 + rep * 1024;
        float4 v = *(const float4*)(s1 + k);
        store4bf(d + k, v.x, v.y, v.z, v.w);
    }
    {
        float4 v = *(const float4*)(s2 + k0);
        store4bf(d + 2048 + k0, v.x, v.y, v.z, v.w);
    }
}

// ---------------------------------------------------------------------------
// WgD pack (decoder): row wr = e16*48 + gate*16 + eL (e in [0,2048)), 1216 cols
__global__ __launch_bounds__(256)
void dgpack_kernel(const float* __restrict__ Wih, bf16* __restrict__ Wg)
{
    const int wr = blockIdx.x;                 // 0..6143
    const int e16 = wr / 48, rem = wr % 48;
    const int gate = rem >> 4, eL = rem & 15;
    const int e = e16 * 16 + eL;
    const float* s = Wih + (size_t)(gate * 2048 + e) * 1216;
    bf16* d = Wg + (size_t)wr * 1216;
    for (int k4 = threadIdx.x; k4 < 304; k4 += 256) {
        float4 v = *(const float4*)(s + k4 * 4);
        store4bf(d + k4 * 4, v.x, v.y, v.z, v.w);
    }
}

// ---------------------------------------------------------------------------
// h0 = annotation(8192,18) @ anno_W(18,1024) -> bf16
__global__ __launch_bounds__(256)
void anno_kernel(const float* __restrict__ anno, const float* __restrict__ W,
                 bf16* __restrict__ Hb)
{
    __shared__ float s[18];
    int row = blockIdx.x;
    if (threadIdx.x < 18) s[threadIdx.x] = anno[row * 18 + threadIdx.x];
    __syncthreads();
    for (int j = threadIdx.x; j < 1024; j += 256) {
        float acc = 0.0f;
#pragma unroll
        for (int k = 0; k < 18; ++k) acc = fmaf(s[k], W[k * 1024 + j], acc);
        Hb[(size_t)row * 1024 + j] = __float2bfloat16(acc);
    }
}

// ---------------------------------------------------------------------------
// fp32 fallback: a = [A_out@H | A_in@H] per batch -> Abuf(8192,2048) bf16
// (H now bf16)
__global__ __launch_bounds__(256)
void bmm_kernel(const float* __restrict__ Aout, const float* __restrict__ Ain,
                const bf16* __restrict__ H, bf16* __restrict__ Abuf)
{
    __shared__ float As[16][68];
    __shared__ float Bs[16][68];
    const int z = blockIdx.z;
    const int b = z >> 1, which = z & 1;
    const float* Amat = (which ? Ain : Aout) + (size_t)b * N_ * N_;
    const bf16* Bmat = H + (size_t)b * N_ * E_;
    const int t = threadIdx.x;
    const int tx = t & 15, ty = t >> 4;
    const int bm = blockIdx.x * 64;
    const int bn = blockIdx.y * 64;
    const int ar = t >> 2, ak = (t & 3) << 2;
    const int kr = t >> 4, kn = (t & 15) << 2;
    float acc[4][4] = {};
    for (int k0 = 0; k0 < N_; k0 += 16) {
        float4 av = *(const float4*)(Amat + (size_t)(bm + ar) * N_ + k0 + ak);
        As[ak + 0][ar] = av.x; As[ak + 1][ar] = av.y;
        As[ak + 2][ar] = av.z; As[ak + 3][ar] = av.w;
        float4 bv = load4bf(Bmat + (size_t)(k0 + kr) * E_ + bn + kn);
        *(float4*)&Bs[kr][kn] = bv;
        __syncthreads();
#pragma unroll
        for (int kk = 0; kk < 16; ++kk) {
            float4 a4 = *(const float4*)&As[kk][ty << 2];
            float4 b4 = *(const float4*)&Bs[kk][tx << 2];
            float am[4] = {a4.x, a4.y, a4.z, a4.w};
            float bb[4] = {b4.x, b4.y, b4.z, b4.w};
#pragma unroll
            for (int i = 0; i < 4; ++i)
#pragma unroll
                for (int j = 0; j < 4; ++j)
                    acc[i][j] = fmaf(am[i], bb[j], acc[i][j]);
        }
        __syncthreads();
    }
#pragma unroll
    for (int i = 0; i < 4; ++i) {
        int row = b * N_ + bm + (ty << 2) + i;
        int col = which * 1024 + bn + (tx << 2);
        store4bf(&Abuf[(size_t)row * 2048 + col], acc[i][0], acc[i][1], acc[i][2], acc[i][3]);
    }
}

// ---------------------------------------------------------------------------
// H(b,256,1024) bf16 -> HbT(b,1024,256) bf16 (tiled transpose)
__global__ __launch_bounds__(256)
void htrans_kernel(const bf16* __restrict__ H, bf16* __restrict__ HbT)
{
    __shared__ float s[64][65];
    const int b = blockIdx.z;
    const int e0 = blockIdx.x * 64;
    const int n0 = blockIdx.y * 64;
    const bf16* Hb = H + (size_t)b * N_ * E_;
    bf16* Tb = HbT + (size_t)b * E_ * N_;
    const int t = threadIdx.x;
    const int tr = t >> 4, tc = (t & 15) << 2;
#pragma unroll
    for (int i = 0; i < 4; ++i) {
        float4 v = load4bf(Hb + (size_t)(n0 + tr + i * 16) * E_ + e0 + tc);
        s[tr + i * 16][tc + 0] = v.x; s[tr + i * 16][tc + 1] = v.y;
        s[tr + i * 16][tc + 2] = v.z; s[tr + i * 16][tc + 3] = v.w;
    }
    __syncthreads();
#pragma unroll
    for (int i = 0; i < 4; ++i) {
        int e = tr + i * 16;
        store4bf(Tb + (size_t)(e0 + e) * N_ + n0 + tc,
                 s[tc + 0][e], s[tc + 1][e], s[tc + 2][e], s[tc + 3][e]);
    }
}

// ---------------------------------------------------------------------------
// MFMA bmm: out[m][n] = sum_k A(256x256)[m][k] * HbT(1024x256)[n][k] per (b,which)
__global__ __launch_bounds__(256)
void bmm_mfma_kernel(const bf16* __restrict__ Aoutb, const bf16* __restrict__ Ainb,
                     const bf16* __restrict__ HbT, bf16* __restrict__ Abuf)
{
    __shared__ bf16 As[64 * 32];
    __shared__ bf16 Bs[64 * 32];
    const int t = threadIdx.x;
    const int lane = t & 63, w = t >> 6;
    const int wm = (w >> 1) * 32, wn = (w & 1) * 32;
    const int z = blockIdx.z, b = z >> 1, which = z & 1;
    const int bm = blockIdx.x * 64, bn = blockIdx.y * 64;
    const int quad = lane >> 4, fr = lane & 15;
    const int srow = t >> 2, slot = t & 3;
    const int g = (slot + ((srow >> 1) & 3)) & 3;
    const int lds_off = srow * 32 + slot * 8;

    f4v acc[2][2];
#pragma unroll
    for (int i = 0; i < 2; ++i)
#pragma unroll
        for (int j = 0; j < 2; ++j) acc[i][j] = (f4v){0.f, 0.f, 0.f, 0.f};

    int aoff[2], boff[2];
#pragma unroll
    for (int i = 0; i < 2; ++i) {
        int arow = wm + 16 * i + fr;
        int s = (quad - ((arow >> 1) & 3)) & 3;
        aoff[i] = arow * 32 + s * 8;
    }
#pragma unroll
    for (int j = 0; j < 2; ++j) {
        int n = wn + 16 * j + fr;
        int s = (quad - ((n >> 1) & 3)) & 3;
        boff[j] = n * 32 + s * 8;
    }

    const bf16* Ap = (which ? Ainb : Aoutb) + (size_t)b * N_ * N_
                   + (size_t)(bm + srow) * N_ + g * 8;
    const bf16* Bp = HbT + (size_t)b * E_ * N_ + (size_t)(bn + srow) * N_ + g * 8;
    for (int k0 = 0; k0 < N_; k0 += 32) {
        float4 av = *(const float4*)(Ap + k0);
        float4 bv4 = *(const float4*)(Bp + k0);
        __syncthreads();
        *(float4*)(As + lds_off) = av;
        *(float4*)(Bs + lds_off) = bv4;
        __syncthreads();
        bf8v af0 = *(const bf8v*)(As + aoff[0]);
        bf8v af1 = *(const bf8v*)(As + aoff[1]);
#pragma unroll
        for (int j = 0; j < 2; ++j) {
            bf8v bv = *(const bf8v*)(Bs + boff[j]);
            MFMA16(acc[0][j], af0, bv);
            MFMA16(acc[1][j], af1, bv);
        }
    }
#pragma unroll
    for (int i = 0; i < 2; ++i)
#pragma unroll
        for (int j = 0; j < 2; ++j)
#pragma unroll
            for (int r = 0; r < 4; ++r) {
                int row = b * N_ + bm + wm + 16 * i + quad * 4 + r;
                int col = which * 1024 + bn + wn + 16 * j + fr;
                Abuf[(size_t)row * 2048 + col] = __float2bfloat16(acc[i][j][r]);
            }
}

// ---------------------------------------------------------------------------
// Fused encoder GRU step as ONE GEMM: X=[a(2048)|h(1024)] @ Wg(3072,3072)^T.
// h is bf16 -> UNIFORM glds16 staging for all K. Counted-vmcnt pipeline:
// 2 tiles in flight, s_waitcnt vmcnt(5) + raw s_barrier (loads stay in flight
// across barriers), stage next-next tile after the read-done barrier.
__global__ __launch_bounds__(256, 2)
void enc_gru_kernel(const bf16* __restrict__ Aab, const bf16* __restrict__ Wg,
                    const bf16* __restrict__ Hcur, bf16* __restrict__ Hnext)
{
    __shared__ __align__(16) bf16 As[2 * 128 * 32];   // 16 KB (2 bufs)
    __shared__ __align__(16) bf16 Bs[2 * 192 * 32];   // 24 KB (2 bufs)
    const int t = threadIdx.x;
    const int lane = t & 63, w = t >> 6;
    const int wm = (w >> 1) * 64;        // wave row base (0/64)
    const int wnH = (w & 1);             // wave e-half (0/1 -> +32 e)
    const int bm = blockIdx.x * 128;
    const int bY = blockIdx.y;           // e in [bY*64, bY*64+64)
    const int quad = lane >> 4, fr = lane & 15;

    f4v ar[2][4], az[2][4], ani[2][4], anh[2][4];
#pragma unroll
    for (int gq = 0; gq < 2; ++gq)
#pragma unroll
        for (int i = 0; i < 4; ++i) {
            ar[gq][i] = (f4v){0.f, 0.f, 0.f, 0.f};
            az[gq][i] = (f4v){0.f, 0.f, 0.f, 0.f};
            ani[gq][i] = (f4v){0.f, 0.f, 0.f, 0.f};
            anh[gq][i] = (f4v){0.f, 0.f, 0.f, 0.f};
        }

    // fragment read offsets (chunk-swizzled, zero-conflict)
    int aoff[4];
#pragma unroll
    for (int i = 0; i < 4; ++i) {
        int row = wm + 16 * i + fr;
        int s = (quad - ((row >> 1) & 3)) & 3;
        aoff[i] = row * 32 + s * 8;
    }
    int boff[2][3];
#pragma unroll
    for (int gq = 0; gq < 2; ++gq)
#pragma unroll
        for (int gt = 0; gt < 3; ++gt) {
            int nb = wnH * 96 + gq * 48 + gt * 16 + fr;
            int s = (quad - ((nb >> 1) & 3)) & 3;
            boff[gq][gt] = nb * 32 + s * 8;
        }

    // staging: lane -> (row-in-16 = lane>>2, slot = lane&3); source chunk g
    const int sr = lane >> 2, ss = lane & 3;
    const int lrA0 = w * 16 + sr;
    const int lrA1 = 64 + w * 16 + sr;
    const int gA0 = (ss + ((lrA0 >> 1) & 3)) & 3;
    const int gA1 = (ss + ((lrA1 >> 1) & 3)) & 3;
    const bf16* apA0 = Aab + (size_t)(bm + lrA0) * 2048 + gA0 * 8;   // a-seg, k<2048
    const bf16* apA1 = Aab + (size_t)(bm + lrA1) * 2048 + gA1 * 8;
    const bf16* hpA0 = Hcur + (size_t)(bm + lrA0) * 1024 + gA0 * 8;  // h-seg, k>=2048
    const bf16* hpA1 = Hcur + (size_t)(bm + lrA1) * 1024 + gA1 * 8;
    const int lrB0 = w * 16 + sr, lrB1 = 64 + w * 16 + sr, lrB2 = 128 + w * 16 + sr;
    const int gB0 = (ss + ((lrB0 >> 1) & 3)) & 3;
    const int gB1 = (ss + ((lrB1 >> 1) & 3)) & 3;
    const int gB2 = (ss + ((lrB2 >> 1) & 3)) & 3;
    const bf16* bp0 = Wg + (size_t)(bY * 192 + lrB0) * 3072 + gB0 * 8;
    const bf16* bp1 = Wg + (size_t)(bY * 192 + lrB1) * 3072 + gB1 * 8;
    const bf16* bp2 = Wg + (size_t)(bY * 192 + lrB2) * 3072 + gB2 * 8;
    const int oA0 = (w * 16) * 32, oA1 = (64 + w * 16) * 32;
    const int oB0 = (w * 16) * 32, oB1 = (64 + w * 16) * 32, oB2 = (128 + w * 16) * 32;

#define ENC_STAGE(K, BUF) do {                                                 \
    const int k_ = (K);                                                        \
    const bf16* a0_ = (k_ < 2048) ? apA0 + k_ : hpA0 + (k_ - 2048);            \
    const bf16* a1_ = (k_ < 2048) ? apA1 + k_ : hpA1 + (k_ - 2048);            \
    glds16(a0_, As + (BUF) * 4096 + oA0);                                      \
    glds16(a1_, As + (BUF) * 4096 + oA1);                                      \
    glds16(bp0 + k_, Bs + (BUF) * 6144 + oB0);                                 \
    glds16(bp1 + k_, Bs + (BUF) * 6144 + oB1);                                 \
    glds16(bp2 + k_, Bs + (BUF) * 6144 + oB2);                                 \
} while (0)

#define ENC_STEP(Ab, Bb, AN) do {                                              \
    bf8v af0 = *(const bf8v*)((Ab) + aoff[0]);                                 \
    bf8v af1 = *(const bf8v*)((Ab) + aoff[1]);                                 \
    bf8v af2 = *(const bf8v*)((Ab) + aoff[2]);                                 \
    bf8v af3 = *(const bf8v*)((Ab) + aoff[3]);                                 \
    _Pragma("unroll")                                                          \
    for (int gq = 0; gq < 2; ++gq) {                                           \
        bf8v br_ = *(const bf8v*)((Bb) + boff[gq][0]);                         \
        bf8v bz_ = *(const bf8v*)((Bb) + boff[gq][1]);                         \
        bf8v bn_ = *(const bf8v*)((Bb) + boff[gq][2]);                         \
        MFMA16(ar[gq][0], af0, br_); MFMA16(ar[gq][1], af1, br_);              \
        MFMA16(ar[gq][2], af2, br_); MFMA16(ar[gq][3], af3, br_);              \
        MFMA16(az[gq][0], af0, bz_); MFMA16(az[gq][1], af1, bz_);              \
        MFMA16(az[gq][2], af2, bz_); MFMA16(az[gq][3], af3, bz_);              \
        MFMA16(AN[gq][0], af0, bn_); MFMA16(AN[gq][1], af1, bn_);              \
        MFMA16(AN[gq][2], af2, bn_); MFMA16(AN[gq][3], af3, bn_);              \
    }                                                                          \
} while (0)

    // prologue: 2 tiles in flight (10 loads/wave)
    ENC_STAGE(0, 0);
    ENC_STAGE(32, 1);
    int cur = 0;
    // invariant at loop top: buf[cur] = tile k0 (oldest 5 loads),
    // buf[cur^1] = tile k0+32 (newest 5); vmcnt(5) completes buf[cur].
#pragma unroll 2
    for (int k0 = 0; k0 < 2048; k0 += 32) {
        asm volatile("s_waitcnt vmcnt(5)" ::: "memory");
        __builtin_amdgcn_s_barrier();
        ENC_STEP(As + cur * 4096, Bs + cur * 6144, ani);
        __builtin_amdgcn_s_barrier();          // all waves done reading buf[cur]
        ENC_STAGE(k0 + 64, cur);               // crosses into h-seg at k=2048
        cur ^= 1;
    }
#pragma unroll 2
    for (int k0 = 2048; k0 < 3040; k0 += 32) {
        asm volatile("s_waitcnt vmcnt(5)" ::: "memory");
        __builtin_amdgcn_s_barrier();
        ENC_STEP(As + cur * 4096, Bs + cur * 6144, anh);
        __builtin_amdgcn_s_barrier();
        if (k0 + 64 < 3072) ENC_STAGE(k0 + 64, cur);
        cur ^= 1;
    }
    // tail: only buf[cur] outstanding (5 loads)
    asm volatile("s_waitcnt vmcnt(0)" ::: "memory");
    __builtin_amdgcn_s_barrier();
    ENC_STEP(As + cur * 4096, Bs + cur * 6144, anh);

    // ---- GRU gate epilogue: all 4 gate values per (row,e) in same lane/reg ----
#pragma unroll
    for (int gq = 0; gq < 2; ++gq) {
        const int e = bY * 64 + wnH * 32 + gq * 16 + fr;
#pragma unroll
        for (int i = 0; i < 4; ++i) {
#pragma unroll
            for (int r = 0; r < 4; ++r) {
                const int row = bm + wm + 16 * i + quad * 4 + r;
                float hv = b2f(Hcur[(size_t)row * 1024 + e]);
                float rg = safe_sigm(ar[gq][i][r]);
                float zg = safe_sigm(az[gq][i][r]);
                float ng = safe_tanh(ani[gq][i][r] + rg * anh[gq][i][r]);
                Hnext[(size_t)row * 1024 + e] =
                    __float2bfloat16((1.0f - zg) * ng + zg * hv);
            }
        }
    }
#undef ENC_STEP
#undef ENC_STAGE
}

// ---------------------------------------------------------------------------
// Fused decoder GRU as ONE GEMM: Cc(8192x1216) @ WgD(6144,1216)^T, h0=0.
// (round-3 proven structure, unchanged)
__global__ __launch_bounds__(256, 2)
void dec_gru_kernel(const bf16* __restrict__ Cc, const bf16* __restrict__ Wg,
                    const float* __restrict__ bih, const float* __restrict__ bhh,
                    float* __restrict__ hidden)
{
    __shared__ __align__(16) bf16 As[2 * 128 * 32];
    __shared__ __align__(16) bf16 Bs[2 * 192 * 32];
    const int t = threadIdx.x;
    const int lane = t & 63, w = t >> 6;
    const int wm = (w >> 1) * 64;
    const int wnH = (w & 1);
    const int bm = blockIdx.x * 128;
    const int bY = blockIdx.y;           // e in [bY*64, bY*64+64), e < 2048
    const int quad = lane >> 4, fr = lane & 15;

    f4v ag[3][2][4];                     // gate, gq, row-frag
#pragma unroll
    for (int c = 0; c < 3; ++c)
#pragma unroll
        for (int gq = 0; gq < 2; ++gq)
#pragma unroll
            for (int i = 0; i < 4; ++i) ag[c][gq][i] = (f4v){0.f, 0.f, 0.f, 0.f};

    int aoff[4];
#pragma unroll
    for (int i = 0; i < 4; ++i) {
        int row = wm + 16 * i + fr;
        int s = (quad - ((row >> 1) & 3)) & 3;
        aoff[i] = row * 32 + s * 8;
    }
    int boff[2][3];
#pragma unroll
    for (int gq = 0; gq < 2; ++gq)
#pragma unroll
        for (int gt = 0; gt < 3; ++gt) {
            int nb = wnH * 96 + gq * 48 + gt * 16 + fr;
            int s = (quad - ((nb >> 1) & 3)) & 3;
            boff[gq][gt] = nb * 32 + s * 8;
        }

    const int sr = lane >> 2, ss = lane & 3;
    const int lrA0 = w * 16 + sr;
    const int lrA1 = 64 + w * 16 + sr;
    const int gA0 = (ss + ((lrA0 >> 1) & 3)) & 3;
    const int gA1 = (ss + ((lrA1 >> 1) & 3)) & 3;
    const bf16* apA0 = Cc + (size_t)(bm + lrA0) * 1216 + gA0 * 8;
    const bf16* apA1 = Cc + (size_t)(bm + lrA1) * 1216 + gA1 * 8;
    const int lrB0 = w * 16 + sr, lrB1 = 64 + w * 16 + sr, lrB2 = 128 + w * 16 + sr;
    const int gB0 = (ss + ((lrB0 >> 1) & 3)) & 3;
    const int gB1 = (ss + ((lrB1 >> 1) & 3)) & 3;
    const int gB2 = (ss + ((lrB2 >> 1) & 3)) & 3;
    const bf16* bp0 = Wg + (size_t)(bY * 192 + lrB0) * 1216 + gB0 * 8;
    const bf16* bp1 = Wg + (size_t)(bY * 192 + lrB1) * 1216 + gB1 * 8;
    const bf16* bp2 = Wg + (size_t)(bY * 192 + lrB2) * 1216 + gB2 * 8;
    const int oA0 = (w * 16) * 32, oA1 = (64 + w * 16) * 32;
    const int oB0 = (w * 16) * 32, oB1 = (64 + w * 16) * 32, oB2 = (128 + w * 16) * 32;

    glds16(apA0, As + oA0);
    glds16(apA1, As + oA1);
    glds16(bp0, Bs + oB0);
    glds16(bp1, Bs + oB1);
    glds16(bp2, Bs + oB2);
    __syncthreads();
    int cur = 0;
    for (int k0 = 0; k0 < 1216; k0 += 32) {
        const int nb = cur ^ 1;
        if (k0 + 32 < 1216) {
            glds16(apA0 + k0 + 32, As + nb * 4096 + oA0);
            glds16(apA1 + k0 + 32, As + nb * 4096 + oA1);
            glds16(bp0 + k0 + 32, Bs + nb * 6144 + oB0);
            glds16(bp1 + k0 + 32, Bs + nb * 6144 + oB1);
            glds16(bp2 + k0 + 32, Bs + nb * 6144 + oB2);
        }
        const bf16* Ab = As + cur * 4096;
        const bf16* Bb = Bs + cur * 6144;
        bf8v af0 = *(const bf8v*)(Ab + aoff[0]);
        bf8v af1 = *(const bf8v*)(Ab + aoff[1]);
        bf8v af2 = *(const bf8v*)(Ab + aoff[2]);
        bf8v af3 = *(const bf8v*)(Ab + aoff[3]);
#pragma unroll
        for (int gq = 0; gq < 2; ++gq) {
            bf8v br_ = *(const bf8v*)(Bb + boff[gq][0]);
            bf8v bz_ = *(const bf8v*)(Bb + boff[gq][1]);
            bf8v bn_ = *(const bf8v*)(Bb + boff[gq][2]);
            MFMA16(ag[0][gq][0], af0, br_); MFMA16(ag[0][gq][1], af1, br_);
            MFMA16(ag[0][gq][2], af2, br_); MFMA16(ag[0][gq][3], af3, br_);
            MFMA16(ag[1][gq][0], af0, bz_); MFMA16(ag[1][gq][1], af1, bz_);
            MFMA16(ag[1][gq][2], af2, bz_); MFMA16(ag[1][gq][3], af3, bz_);
            MFMA16(ag[2][gq][0], af0, bn_); MFMA16(ag[2][gq][1], af1, bn_);
            MFMA16(ag[2][gq][2], af2, bn_); MFMA16(ag[2][gq][3], af3, bn_);
        }
        __syncthreads();
        cur = nb;
    }

#pragma unroll
    for (int gq = 0; gq < 2; ++gq) {
        const int e = bY * 64 + wnH * 32 + gq * 16 + fr;
        const float br = bih[e] + bhh[e];
        const float bz = bih[2048 + e] + bhh[2048 + e];
        const float bni = bih[4096 + e];
        const float bnh = bhh[4096 + e];
#pragma unroll
        for (int i = 0; i < 4; ++i) {
#pragma unroll
            for (int r = 0; r < 4; ++r) {
                const int row = bm + wm + 16 * i + quad * 4 + r;
                float rr = safe_sigm(ag[0][gq][i][r] + br);
                float zz = safe_sigm(ag[1][gq][i][r] + bz);
                float nn = safe_tanh(ag[2][gq][i][r] + bni + rr * bnh);
                hidden[(size_t)row * 2048 + e] = (1.0f - zz) * nn;
            }
        }
    }
}

// ---------------------------------------------------------------------------
__global__ __launch_bounds__(128)
void vnva_kernel(const float* __restrict__ vnf_now, const float* __restrict__ vnf_all,
                 const float* __restrict__ Wn, const float* __restrict__ Wa,
                 float* __restrict__ vn, float* __restrict__ va)
{
    int b = blockIdx.x, t = threadIdx.x;
    if (t < 64) {
        float s = 0.f;
#pragma unroll
        for (int k = 0; k < 16; ++k) s = fmaf(vnf_now[b * 16 + k], Wn[k * 64 + t], s);
        vn[b * 64 + t] = s;
    } else {
        int d = t - 64;
        float s = 0.f;
#pragma unroll
        for (int k = 0; k < 16; ++k) s = fmaf(vnf_all[b * 16 + k], Wa[k * 64 + d], s);
        va[b * 64 + d] = s;
    }
}

// concat(row,1216) = [ enc_out(1024, bf16 passthrough) | npos | va | vn ] -> bf16
__global__ __launch_bounds__(256)
void concat_kernel(const bf16* __restrict__ H, const float* __restrict__ pos_enc,
                   const int* __restrict__ from_node, const float* __restrict__ va,
                   const float* __restrict__ vn, bf16* __restrict__ Cc)
{
    int row = blockIdx.x;
    int b = row >> 8;
    int fn = from_node[b];
    const bf16* hsrc = H + (size_t)row * 1024;
    bf16* dst = Cc + (size_t)row * 1216;
    for (int c8 = threadIdx.x; c8 < 152; c8 += 256) {
        int c = c8 * 8;
        if (c < 1024) {
            *(uint4*)(dst + c) = *(const uint4*)(hsrc + c);
        } else {
#pragma unroll
            for (int j = 0; j < 8; ++j) {
                int col = c + j;
                float v;
                if (col < 1088)      v = pos_enc[fn * 64 + (col - 1024)];
                else if (col < 1152) v = va[b * 64 + (col - 1088)];
                else                 v = vn[b * 64 + (col - 1152)];
                dst[col] = __float2bfloat16(v);
            }
        }
    }
}

// ---------------------------------------------------------------------------
// MFMA out1: mid = relu(hidden(8192x2048 fp32, inline->bf16) @ W1b^T + b1) -> bf16
__global__ __launch_bounds__(256)
void out1_mfma_kernel(const float* __restrict__ H, const bf16* __restrict__ W1b,
                      const float* __restrict__ bias, bf16* __restrict__ mid)
{
    __shared__ bf16 As[64 * 32];
    __shared__ bf16 Ws[256 * 32];
    const int t = threadIdx.x;
    const int lane = t & 63, w = t >> 6;
    const int bm = blockIdx.x * 64, bn = blockIdx.y * 256;
    const int quad = lane >> 4, fr = lane & 15;
    const int srow = t >> 2, slot = t & 3;
    const int g = (slot + ((srow >> 1) & 3)) & 3;
    const int lds_off = srow * 32 + slot * 8;

    f4v acc[4][4];
#pragma unroll
    for (int i = 0; i < 4; ++i)
#pragma unroll
        for (int j = 0; j < 4; ++j) acc[i][j] = (f4v){0.f, 0.f, 0.f, 0.f};

    int aoff[4], boff[4];
#pragma unroll
    for (int i = 0; i < 4; ++i) {
        int arow = 16 * i + fr;
        int s = (quad - ((arow >> 1) & 3)) & 3;
        aoff[i] = arow * 32 + s * 8;
    }
#pragma unroll
    for (int j = 0; j < 4; ++j) {
        int n = w * 64 + 16 * j + fr;
        int s = (quad - ((n >> 1) & 3)) & 3;
        boff[j] = n * 32 + s * 8;
    }

    const float* Hp = H + (size_t)(bm + srow) * 2048 + g * 8;
    const bf16* Wp0 = W1b + (size_t)(bn + srow) * 2048 + g * 8;
    const bf16* Wp1 = W1b + (size_t)(bn + srow + 64) * 2048 + g * 8;
    const bf16* Wp2 = W1b + (size_t)(bn + srow + 128) * 2048 + g * 8;
    const bf16* Wp3 = W1b + (size_t)(bn + srow + 192) * 2048 + g * 8;

    for (int k0 = 0; k0 < 2048; k0 += 32) {
        float4 h0 = *(const float4*)(Hp + k0);
        float4 h1 = *(const float4*)(Hp + k0 + 4);
        float4 w0 = *(const float4*)(Wp0 + k0);
        float4 w1 = *(const float4*)(Wp1 + k0);
        float4 w2 = *(const float4*)(Wp2 + k0);
        float4 w3 = *(const float4*)(Wp3 + k0);
        uint4 pk;
        pk.x = (unsigned)f2bu(h0.x) | ((unsigned)f2bu(h0.y) << 16);
        pk.y = (unsigned)f2bu(h0.z) | ((unsigned)f2bu(h0.w) << 16);
        pk.z = (unsigned)f2bu(h1.x) | ((unsigned)f2bu(h1.y) << 16);
        pk.w = (unsigned)f2bu(h1.z) | ((unsigned)f2bu(h1.w) << 16);
        __syncthreads();
        *(uint4*)(As + lds_off) = pk;
        *(float4*)(Ws + lds_off) = w0;
        *(float4*)(Ws + 2048 + lds_off) = w1;
        *(float4*)(Ws + 4096 + lds_off) = w2;
        *(float4*)(Ws + 6144 + lds_off) = w3;
        __syncthreads();
        bf8v af0 = *(const bf8v*)(As + aoff[0]);
        bf8v af1 = *(const bf8v*)(As + aoff[1]);
        bf8v af2 = *(const bf8v*)(As + aoff[2]);
        bf8v af3 = *(const bf8v*)(As + aoff[3]);
#pragma unroll
        for (int j = 0; j < 4; ++j) {
            bf8v bv = *(const bf8v*)(Ws + boff[j]);
            MFMA16(acc[0][j], af0, bv);
            MFMA16(acc[1][j], af1, bv);
            MFMA16(acc[2][j], af2, bv);
            MFMA16(acc[3][j], af3, bv);
        }
    }
#pragma unroll
    for (int j = 0; j < 4; ++j) {
        const int col = bn + w * 64 + 16 * j + fr;
        const float bb = bias[col];
#pragma unroll
        for (int i = 0; i < 4; ++i) {
#pragma unroll
            for (int r = 0; r < 4; ++r) {
                const int row = bm + 16 * i + quad * 4 + r;
                mid[(size_t)row * 1024 + col] = __float2bfloat16(fmaxf(acc[i][j][r] + bb, 0.0f));
            }
        }
    }
}

// ---------------------------------------------------------------------------
__global__ __launch_bounds__(64)
void out2_kernel(const bf16* __restrict__ mid, const float* __restrict__ W2,
                 const float* __restrict__ b2, float* __restrict__ outb)
{
    int row = blockIdx.x, t = threadIdx.x;
    float s0 = 0.f, s1 = 0.f, s2 = 0.f;
    for (int k = t; k < 1024; k += 64) {
        float m = b2f(mid[(size_t)row * 1024 + k]);
        s0 = fmaf(m, W2[k], s0);
        s1 = fmaf(m, W2[1024 + k], s1);
        s2 = fmaf(m, W2[2048 + k], s2);
    }
#pragma unroll
    for (int off = 32; off > 0; off >>= 1) {
        s0 += __shfl_down(s0, off, 64);
        s1 += __shfl_down(s1, off, 64);
        s2 += __shfl_down(s2, off, 64);
    }
    if (t == 0) {
        outb[row * 3 + 0] = s0 + b2[0];
        outb[row * 3 + 1] = s1 + b2[1];
        outb[row * 3 + 2] = s2 + b2[2];
    }
}

__global__ __launch_bounds__(64)
void max_kernel(const float* __restrict__ outb, float* __restrict__ maxb)
{
    int b = blockIdx.x, t = threadIdx.x;
    float m = -3.0e38f;
    for (int i = t; i < 768; i += 64) m = fmaxf(m, outb[b * 768 + i]);
#pragma unroll
    for (int off = 32; off > 0; off >>= 1) m = fmaxf(m, __shfl_down(m, off, 64));
    if (t == 0) maxb[b] = m;
}

__global__ __launch_bounds__(256)
void mask_kernel(const float* __restrict__ outb, const float* __restrict__ maxb,
                 const int* __restrict__ mask, float* __restrict__ out)
{
    int idx = blockIdx.x * 256 + threadIdx.x;
    if (idx >= BN_ * 3) return;
    int row = idx / 3, c = idx - row * 3;
    int b = row >> 8;
    float v = outb[idx] - (maxb[b] + 1.0f);
    float mf = (mask[row] == 1) ? 1.0f : 1e10f;
    v = mf * v + 1.0f;
    if (c == 0) out[row] = v;
    else        out[8192 + row * 2 + (c - 1)] = v;
}

// ---------------------------------------------------------------------------
extern "C" void kernel_launch(void* const* d_in, const int* in_sizes, int n_in,
                              void* d_out, int out_size, void* d_ws, size_t ws_size,
                              hipStream_t stream)
{
    const float* annotation = (const float*)d_in[0];
    const float* A_out      = (const float*)d_in[1];
    const float* A_in       = (const float*)d_in[2];
    const int*   from_node  = (const int*)d_in[3];
    const float* vnf_now    = (const float*)d_in[4];
    const float* vnf_all    = (const float*)d_in[5];
    const int*   mask       = (const int*)d_in[6];
    const float* anno_W     = (const float*)d_in[7];
    const float* gru_Wih    = (const float*)d_in[8];
    const float* gru_Whh    = (const float*)d_in[9];
    const float* vnf_now_W  = (const float*)d_in[10];
    const float* vnf_all_W  = (const float*)d_in[11];
    const float* dgru_Wih   = (const float*)d_in[12];
    // d_in[13] dgru_Whh dead: h0 == 0
    const float* dgru_bih   = (const float*)d_in[14];
    const float* dgru_bhh   = (const float*)d_in[15];
    const float* out_W1     = (const float*)d_in[16];
    const float* out_b1     = (const float*)d_in[17];
    const float* out_W2     = (const float*)d_in[18];
    const float* out_b2     = (const float*)d_in[19];
    const float* pos_enc    = (const float*)d_in[20];
    float* out = (float*)d_out;

    // ws layout (identical footprint to round 3):
    bf16*  Abuf = (bf16*)d_ws;                        // 8192*2048
    bf16*  Wenc = Abuf + (size_t)8192 * 2048;         // 9,437,184 bf16
    bf16*  Wg   = Wenc;                               // 3072*3072
    bf16*  WgD  = Wenc;                               // 6144*1216 fits
    bf16*  W1b  = Wenc;                               // 1024*2048 fits
    float* fbuf = (float*)(Wenc + (size_t)9437184);
    float* vnb  = fbuf;            // 32*64
    float* vab  = vnb + 2048;      // 32*64
    float* outb = vab + 2048;      // 8192*3
    float* maxb = outb + 24576;    // 32
    bf16*  Aoutb = (bf16*)(maxb + 32);                // 32*256*256
    bf16*  Ainb  = Aoutb + (size_t)32 * 256 * 256;    // 32*256*256
    bf16*  HbT   = Ainb + (size_t)32 * 256 * 256;     // 32*1024*256

    const size_t NEED_FULL = (size_t)(16777216 + 9437184) * 2 + 28704 * 4
                           + (size_t)(4194304 + 8388608) * 2;   // 77,709,440 B
    const bool full = ws_size >= NEED_FULL;

    // h as bf16 ping-pong inside d_out's hidden slot (dec_gru overwrites later)
    float* hidden = out + 24576;
    bf16* Hb0 = (bf16*)hidden;                        // 8192*1024 bf16
    bf16* Hb1 = Hb0 + (size_t)8192 * 1024;            // 8192*1024 bf16
    bf16* Cc  = Abuf;              // concat 8192x1216 bf16 (after a dead)
    bf16* mid = Abuf;              // 8192x1024 bf16 (after concat dead)

    // weight prepass (same work every launch — graph-capture safe)
    wgpack_kernel<<<3072, 256, 0, stream>>>(gru_Wih, gru_Whh, Wg);
    if (full) {
        w2bf_kernel<<<2048, 256, 0, stream>>>(A_out, Aoutb, 32 * 256 * 256 / 4);
        w2bf_kernel<<<2048, 256, 0, stream>>>(A_in,  Ainb,  32 * 256 * 256 / 4);
    }

    anno_kernel<<<8192, 256, 0, stream>>>(annotation, anno_W, Hb0);

    const bf16* hc = Hb0;
    bf16* hn = Hb1;
    for (int s = 0; s < 5; ++s) {
        if (full) {
            htrans_kernel<<<dim3(16, 4, 32), 256, 0, stream>>>(hc, HbT);
            bmm_mfma_kernel<<<dim3(4, 16, 64), 256, 0, stream>>>(Aoutb, Ainb, HbT, Abuf);
        } else {
            bmm_kernel<<<dim3(4, 16, 64), 256, 0, stream>>>(A_out, A_in, hc, Abuf);
        }
        enc_gru_kernel<<<dim3(64, 16), 256, 0, stream>>>(Abuf, Wg, hc, hn);
        bf16* tmp = (bf16*)hc; hc = hn; hn = tmp;
    }
    // hc == Hb1 after 5 steps

    vnva_kernel<<<32, 128, 0, stream>>>(vnf_now, vnf_all, vnf_now_W, vnf_all_W, vnb, vab);
    concat_kernel<<<8192, 256, 0, stream>>>(hc, pos_enc, from_node, vab, vnb, Cc);

    // enc weights dead -> pack decoder weight into the same region
    dgpack_kernel<<<6144, 256, 0, stream>>>(dgru_Wih, WgD);
    dec_gru_kernel<<<dim3(64, 32), 256, 0, stream>>>(Cc, WgD, dgru_bih, dgru_bhh, hidden);

    // decoder weight dead -> convert out_W1 into the same region
    w2bf_kernel<<<2048, 256, 0, stream>>>(out_W1, W1b, 1024 * 2048 / 4);
    out1_mfma_kernel<<<dim3(128, 4), 256, 0, stream>>>(hidden, W1b, out_b1, mid);

    out2_kernel<<<8192, 64, 0, stream>>>(mid, out_W2, out_b2, outb);
    max_kernel<<<32, 64, 0, stream>>>(outb, maxb);
    mask_kernel<<<96, 256, 0, stream>>>(outb, maxb, mask, out);
}